// Round 15
// baseline (333.545 us; speedup 1.0000x reference)
//
#include <hip/hip_runtime.h>
#include <hip/hip_fp16.h>

#define DD 64
#define HC 384     // 2*D*L
#define SS 32
#define BINW 256   // nodes per bin (bin = dst >> 8); requires N < 65536
#define BSH 8
#define CAP 8192   // slab capacity per bin (avg load 4096 at E=800k)
#define CHUNK 4096 // edges per partition block

// ---------------- prep: bin_cur init + hcat zero + x->fp16 ----------------
__global__ __launch_bounds__(256) void prep_kernel(
    const float* __restrict__ x, __half* __restrict__ hh0,
    int* __restrict__ bin_cur, float* __restrict__ hcat,
    int nbins, int hcat4, int total)
{
  int gid = blockIdx.x * 256 + threadIdx.x;
  if (gid < nbins) bin_cur[gid] = gid * CAP;
  if (gid < hcat4) ((float4*)hcat)[gid] = make_float4(0.f, 0.f, 0.f, 0.f);
  int i = gid * 8;
  if (i < total) {
    float4 a = *(const float4*)(x + i);
    float4 b = *(const float4*)(x + i + 4);
    __half2 o[4];
    o[0] = __floats2half2_rn(a.x, a.y);
    o[1] = __floats2half2_rn(a.z, a.w);
    o[2] = __floats2half2_rn(b.x, b.y);
    o[3] = __floats2half2_rn(b.z, b.w);
    *(float4*)(hh0 + i) = *(float4*)o;
  }
}

// ---------------- partition edges into dst-bin slabs ----------------
__global__ __launch_bounds__(256) void bin_part_kernel(
    const int* __restrict__ ei, const float* __restrict__ ew,
    int* __restrict__ bin_cur, unsigned* __restrict__ pk_slab,
    unsigned short* __restrict__ dl_slab, int E)
{
  __shared__ unsigned spk[CHUNK];         // 16 KB
  __shared__ unsigned short sdst[CHUNK];  // 8 KB
  __shared__ int bcnt[256], boff[256], bcur[256], gbase[256], stmp[256];
  int t = threadIdx.x;
  int e0 = blockIdx.x * CHUNK;
  int m = min(CHUNK, E - e0);
  bcnt[t] = 0;
  __syncthreads();
  for (int i = t; i < m; i += 256)
    atomicAdd(&bcnt[ei[E + e0 + i] >> BSH], 1);
  __syncthreads();
  int v = bcnt[t];
  stmp[t] = v;
  __syncthreads();
  for (int o = 1; o < 256; o <<= 1) {
    int u = (t >= o) ? stmp[t - o] : 0;
    __syncthreads();
    stmp[t] += u;
    __syncthreads();
  }
  boff[t] = stmp[t] - v;
  bcur[t] = stmp[t] - v;
  if (v > 0) gbase[t] = atomicAdd(&bin_cur[t], v);
  __syncthreads();
  for (int i = t; i < m; i += 256) {
    unsigned d = (unsigned)ei[E + e0 + i];
    int b = d >> BSH;
    int p = atomicAdd(&bcur[b], 1);
    unsigned short wh = __half_as_ushort(__float2half(ew[e0 + i]));
    spk[p] = (unsigned)ei[e0 + i] | ((unsigned)wh << 16);
    sdst[p] = (unsigned short)d;
  }
  __syncthreads();
  for (int i = t; i < m; i += 256) {
    unsigned short d = sdst[i];
    int b = d >> BSH;
    int g = gbase[b] + (i - boff[b]);
    pk_slab[g] = spk[i];
    dl_slab[g] = d;
  }
}

// one block per bin: local hist + scan -> beg/end[], scatter 4-byte
// records into the bin's own slab window of packed[] (L2-resident)
__global__ __launch_bounds__(256) void fine_csr_kernel(
    const unsigned* __restrict__ pk_slab,
    const unsigned short* __restrict__ dl_slab,
    const int* __restrict__ bin_cur, int* __restrict__ beg,
    int* __restrict__ endo, unsigned* __restrict__ packed, int N)
{
  __shared__ int cnt[256], loff[256], cur[256], stmp[256];
  int t = threadIdx.x;
  int b = blockIdx.x;
  int sbase = b * CAP;
  int m = bin_cur[b] - sbase;
  cnt[t] = 0;
  __syncthreads();
  for (int i = t; i < m; i += 256)
    atomicAdd(&cnt[dl_slab[sbase + i] & 255], 1);
  __syncthreads();
  int v = cnt[t];
  stmp[t] = v;
  __syncthreads();
  for (int o = 1; o < 256; o <<= 1) {
    int u = (t >= o) ? stmp[t - o] : 0;
    __syncthreads();
    stmp[t] += u;
    __syncthreads();
  }
  loff[t] = stmp[t] - v;
  cur[t] = loff[t];
  int node = b * BINW + t;
  if (node < N) {
    beg[node] = sbase + loff[t];
    endo[node] = sbase + loff[t] + v;
  }
  __syncthreads();
  for (int i = t; i < m; i += 256) {
    int dl = dl_slab[sbase + i] & 255;
    int p = atomicAdd(&cur[dl], 1);
    packed[sbase + p] = pk_slab[sbase + i];
  }
}

// ---------------- gather + z: FOUR nodes per wave (4x MLP) ----------------
// 8 edge-subgroups x 8 lanes; lane holds 8 channels (16 B fp16 row).
// Four independent edge-list chains per lane hide L2-miss latency.
// z written fp16 (node re-quantizes anyway; error << threshold).
__global__ __launch_bounds__(256) void gather_kernel(
    const __half* __restrict__ hh, const unsigned* __restrict__ packed,
    const int* __restrict__ begA, const int* __restrict__ endA,
    const float* __restrict__ epsv, __half* __restrict__ zh, int layer, int N)
{
  int wave = threadIdx.x >> 6;
  int lane = threadIdx.x & 63;
  int sub = lane >> 3;          // 0..7
  int ch0 = (lane & 7) * 8;     // 8 channels per lane
  int n0 = blockIdx.x * 16 + wave * 4;
  if (n0 >= N) return;
  int e[4], en[4];
  #pragma unroll
  for (int q = 0; q < 4; ++q) {
    int n = n0 + q;
    bool ok = n < N;
    e[q]  = ok ? begA[n] + sub : 0;
    en[q] = ok ? endA[n] : 0;
  }
  float acc[4][8] = {};
  while (e[0] < en[0] || e[1] < en[1] || e[2] < en[2] || e[3] < en[3]) {
    unsigned p[4];
    float4 r[4];
    #pragma unroll
    for (int q = 0; q < 4; ++q)
      if (e[q] < en[q]) p[q] = packed[e[q]];
    #pragma unroll
    for (int q = 0; q < 4; ++q)
      if (e[q] < en[q])
        r[q] = *(const float4*)(hh + (size_t)(p[q] & 0xffffu) * DD + ch0);
    #pragma unroll
    for (int q = 0; q < 4; ++q) {
      if (e[q] < en[q]) {
        float w = __half2float(__ushort_as_half((unsigned short)(p[q] >> 16)));
        const __half2* H = (const __half2*)&r[q];
        #pragma unroll
        for (int j = 0; j < 4; ++j) {
          float2 f = __half22float2(H[j]);
          acc[q][2 * j]     = fmaf(w, f.x, acc[q][2 * j]);
          acc[q][2 * j + 1] = fmaf(w, f.y, acc[q][2 * j + 1]);
        }
      }
      e[q] += 8;
    }
  }
  #pragma unroll
  for (int q = 0; q < 4; ++q)
    #pragma unroll
    for (int j = 0; j < 8; ++j) {
      acc[q][j] += __shfl_xor(acc[q][j], 8);
      acc[q][j] += __shfl_xor(acc[q][j], 16);
      acc[q][j] += __shfl_xor(acc[q][j], 32);
    }
  if (sub == 0) {
    float e1 = 1.0f + epsv[layer];
    #pragma unroll
    for (int q = 0; q < 4; ++q) {
      int n = n0 + q;
      if (n >= N) break;
      float4 sr = *(const float4*)(hh + (size_t)n * DD + ch0);
      const __half2* S = (const __half2*)&sr;
      float2 s0 = __half22float2(S[0]), s1 = __half22float2(S[1]);
      float2 s2 = __half22float2(S[2]), s3 = __half22float2(S[3]);
      __half2 o[4];
      o[0] = __floats2half2_rn(fmaf(e1, s0.x, acc[q][0]),
                               fmaf(e1, s0.y, acc[q][1]));
      o[1] = __floats2half2_rn(fmaf(e1, s1.x, acc[q][2]),
                               fmaf(e1, s1.y, acc[q][3]));
      o[2] = __floats2half2_rn(fmaf(e1, s2.x, acc[q][4]),
                               fmaf(e1, s2.y, acc[q][5]));
      o[3] = __floats2half2_rn(fmaf(e1, s3.x, acc[q][6]),
                               fmaf(e1, s3.y, acc[q][7]));
      *(float4*)(zh + (size_t)n * DD + ch0) = *(float4*)o;
    }
  }
}

// ---------------- per-node GIN MLP + pooling ----------------
// Block = 256 (4 waves) = 64 nodes; waves split 64 output channels
// (16 each). c0 in SGPR via readfirstlane -> all W/BN loads scalar.
__global__ __launch_bounds__(256) void node_kernel(
    const __half* __restrict__ zh, __half* __restrict__ hhout,
    const float* __restrict__ W1, const float* __restrict__ b1,
    const float* __restrict__ gamma, const float* __restrict__ beta,
    const float* __restrict__ bnm, const float* __restrict__ bnv,
    const float* __restrict__ W2, const float* __restrict__ b2,
    const float* __restrict__ pmask, const int* __restrict__ batch,
    float* __restrict__ hcat, int layer, int N)
{
  __shared__ float tileZ[DD * DD];
  __shared__ float tileT[DD * DD];
  const int wave = threadIdx.x >> 6;
  const int lane = threadIdx.x & 63;
  const int n0 = blockIdx.x * 64;
  const int c0 = __builtin_amdgcn_readfirstlane(wave * 16);  // SGPR
  const float* W1l = W1 + layer * DD * DD;
  const float* W2l = W2 + layer * DD * DD;

  #pragma unroll
  for (int i = 0; i < 16; ++i) {
    int r = c0 + i;
    int n = n0 + r;
    float v = (n < N) ? __half2float(zh[(size_t)n * DD + lane]) : 0.0f;
    tileZ[r * DD + ((lane + r) & 63)] = v;
  }
  __syncthreads();

  float t[16];
  #pragma unroll
  for (int cc = 0; cc < 16; ++cc) t[cc] = 0.0f;
  #pragma unroll 2
  for (int k = 0; k < DD; ++k) {
    float zk = tileZ[lane * DD + ((k + lane) & 63)];
    #pragma unroll
    for (int cc = 0; cc < 16; ++cc)
      t[cc] = fmaf(zk, W1l[k * DD + c0 + cc], t[cc]);   // scalar W
  }
  #pragma unroll
  for (int cc = 0; cc < 16; ++cc) {
    int c = c0 + cc;
    float A = gamma[layer * DD + c] * rsqrtf(bnv[layer * DD + c] + 1e-5f);
    float B = fmaf(b1[layer * DD + c] - bnm[layer * DD + c], A,
                   beta[layer * DD + c]);
    tileT[lane * DD + ((c + lane) & 63)] = fmaxf(fmaf(t[cc], A, B), 0.0f);
  }
  __syncthreads();

  #pragma unroll
  for (int cc = 0; cc < 16; ++cc) t[cc] = 0.0f;
  #pragma unroll 2
  for (int k = 0; k < DD; ++k) {
    float zk = tileT[lane * DD + ((k + lane) & 63)];
    #pragma unroll
    for (int cc = 0; cc < 16; ++cc)
      t[cc] = fmaf(zk, W2l[k * DD + c0 + cc], t[cc]);   // scalar W
  }
  #pragma unroll
  for (int cc = 0; cc < 16; ++cc) {
    int c = c0 + cc;
    tileZ[lane * DD + ((c + lane) & 63)] =
        fmaxf(t[cc] + b2[layer * DD + c], 0.0f);
  }
  __syncthreads();

  float accp = 0.0f;
  int gcur = -1;
  for (int i = 0; i < 16; ++i) {
    int r = c0 + i;
    int n = n0 + r;
    if (n >= N) break;
    float v = tileZ[r * DD + ((lane + r) & 63)];
    hhout[(size_t)n * DD + lane] = __float2half(v);
    int g = batch[n];                    // wave-uniform -> s_load
    if (g != gcur) {
      if (gcur >= 0) atomicAdd(&hcat[gcur * HC + layer * 128 + lane], accp);
      gcur = g; accp = 0.0f;
    }
    accp = fmaf(v, pmask[n], accp);
  }
  if (gcur >= 0) atomicAdd(&hcat[gcur * HC + layer * 128 + lane], accp);
}

// ---------------- final linear (+ fp16 center gather fused) ----------------
__global__ __launch_bounds__(256) void final_kernel(
    const float* __restrict__ hcat, const __half* __restrict__ h1,
    const __half* __restrict__ h2, const __half* __restrict__ h3,
    const int* __restrict__ mapping, const float* __restrict__ lw,
    const float* __restrict__ lb, float* __restrict__ out, int G)
{
  int gid = blockIdx.x * 256 + threadIdx.x;
  int g = gid >> 5, s = gid & 31;
  if (g >= G) return;
  float acc = lb[s];
  size_t mrow = (size_t)mapping[g] * DD;
  #pragma unroll
  for (int l = 0; l < 3; ++l) {
    const float* hc = hcat + g * HC + l * 128;
    const float* lwa = lw + (l * 128) * SS + s;
    #pragma unroll 4
    for (int c = 0; c < 64; ++c)
      acc = fmaf(hc[c], lwa[c * SS], acc);
    const __half* hr = ((l == 0) ? h1 : ((l == 1) ? h2 : h3)) + mrow;
    const float* lwc = lw + (l * 128 + 64) * SS + s;
    #pragma unroll 4
    for (int c = 0; c < 64; ++c)
      acc = fmaf(__half2float(hr[c]), lwc[c * SS], acc);
  }
  out[g * SS + s] = acc;
}

extern "C" void kernel_launch(void* const* d_in, const int* in_sizes, int n_in,
                              void* d_out, int out_size, void* d_ws, size_t ws_size,
                              hipStream_t stream)
{
  const float* x     = (const float*)d_in[0];
  const float* ew    = (const float*)d_in[1];
  const float* pmask = (const float*)d_in[2];
  const float* W1    = (const float*)d_in[3];
  const float* b1    = (const float*)d_in[4];
  const float* gma   = (const float*)d_in[5];
  const float* bta   = (const float*)d_in[6];
  const float* bnm   = (const float*)d_in[7];
  const float* bnv   = (const float*)d_in[8];
  const float* W2    = (const float*)d_in[9];
  const float* b2    = (const float*)d_in[10];
  const float* epsv  = (const float*)d_in[11];
  const float* lw    = (const float*)d_in[12];
  const float* lb    = (const float*)d_in[13];
  const int*   ei    = (const int*)d_in[14];
  const int*   batch = (const int*)d_in[15];
  const int*   mapping = (const int*)d_in[16];

  const int N = in_sizes[2];     // 50000 (< 65536 required for packing)
  const int E = in_sizes[1];
  const int G = in_sizes[16];
  const int nbins = (N + BINW - 1) / BINW;   // 196 <= 256
  const int nchunks = (E + CHUNK - 1) / CHUNK;

  __half*   hh0  = (__half*)d_ws;                     // N*DD fp16
  __half*   hh1  = hh0 + (size_t)N * DD;              // N*DD
  __half*   hh2  = hh1 + (size_t)N * DD;              // N*DD
  __half*   hh3  = hh2 + (size_t)N * DD;              // N*DD
  __half*   zh   = hh3 + (size_t)N * DD;              // N*DD fp16 z
  float*    hcat = (float*)(zh + (size_t)N * DD);     // G*HC
  int*      beg  = (int*)(hcat + (size_t)G * HC);     // N
  int*      endo = beg + N;                           // N
  int*      bin_cur = endo + N;                       // nbins (+pad)
  unsigned* packed  = (unsigned*)(bin_cur + 256);     // nbins*CAP
  unsigned* pk_slab = packed + (size_t)nbins * CAP;   // nbins*CAP
  unsigned short* dl_slab =
      (unsigned short*)(pk_slab + (size_t)nbins * CAP); // nbins*CAP
  float* fout = (float*)d_out;

  // ---- prep (bin_cur init + hcat zero + x->fp16), 1 dispatch ----
  prep_kernel<<<(N * DD / 8 + 255) / 256, 256, 0, stream>>>(
      x, hh0, bin_cur, hcat, nbins, G * HC / 4, N * DD);

  // ---- slab-binned CSR build (2 dispatches) ----
  bin_part_kernel<<<nchunks, 256, 0, stream>>>(ei, ew, bin_cur,
                                               pk_slab, dl_slab, E);
  fine_csr_kernel<<<nbins, 256, 0, stream>>>(pk_slab, dl_slab, bin_cur,
                                             beg, endo, packed, N);

  // ---- 3 GIN layers ----
  __half* hhs[4] = {hh0, hh1, hh2, hh3};
  for (int layer = 0; layer < 3; ++layer) {
    gather_kernel<<<(N + 15) / 16, 256, 0, stream>>>(
        hhs[layer], packed, beg, endo, epsv, zh, layer, N);
    node_kernel<<<(N + 63) / 64, 256, 0, stream>>>(
        zh, hhs[layer + 1], W1, b1, gma, bta, bnm, bnv, W2, b2,
        pmask, batch, hcat, layer, N);
  }
  final_kernel<<<(G * SS + 255) / 256, 256, 0, stream>>>(
      hcat, hh1, hh2, hh3, mapping, lw, lb, fout, G);
}

// Round 16
// 312.571 us; speedup vs baseline: 1.0671x; 1.0671x over previous
//
#include <hip/hip_runtime.h>
#include <hip/hip_fp16.h>

#define DD 64
#define HC 384     // 2*D*L
#define SS 32
#define BINW 256   // nodes per bin (bin = dst >> 8); requires N < 65536
#define BSH 8
#define CAP 8192   // slab capacity per bin (avg load 4096 at E=800k)
#define CHUNK 4096 // edges per partition block

// ---------------- prep: bin_cur init + hcat zero + x->fp16 ----------------
__global__ __launch_bounds__(256) void prep_kernel(
    const float* __restrict__ x, __half* __restrict__ hh0,
    int* __restrict__ bin_cur, float* __restrict__ hcat,
    int nbins, int hcat4, int total)
{
  int gid = blockIdx.x * 256 + threadIdx.x;
  if (gid < nbins) bin_cur[gid] = gid * CAP;
  if (gid < hcat4) ((float4*)hcat)[gid] = make_float4(0.f, 0.f, 0.f, 0.f);
  int i = gid * 8;
  if (i < total) {
    float4 a = *(const float4*)(x + i);
    float4 b = *(const float4*)(x + i + 4);
    __half2 o[4];
    o[0] = __floats2half2_rn(a.x, a.y);
    o[1] = __floats2half2_rn(a.z, a.w);
    o[2] = __floats2half2_rn(b.x, b.y);
    o[3] = __floats2half2_rn(b.z, b.w);
    *(float4*)(hh0 + i) = *(float4*)o;
  }
}

// ---------------- partition edges into dst-bin slabs ----------------
__global__ __launch_bounds__(256) void bin_part_kernel(
    const int* __restrict__ ei, const float* __restrict__ ew,
    int* __restrict__ bin_cur, unsigned* __restrict__ pk_slab,
    unsigned short* __restrict__ dl_slab, int E)
{
  __shared__ unsigned spk[CHUNK];         // 16 KB
  __shared__ unsigned short sdst[CHUNK];  // 8 KB
  __shared__ int bcnt[256], boff[256], bcur[256], gbase[256], stmp[256];
  int t = threadIdx.x;
  int e0 = blockIdx.x * CHUNK;
  int m = min(CHUNK, E - e0);
  bcnt[t] = 0;
  __syncthreads();
  for (int i = t; i < m; i += 256)
    atomicAdd(&bcnt[ei[E + e0 + i] >> BSH], 1);
  __syncthreads();
  int v = bcnt[t];
  stmp[t] = v;
  __syncthreads();
  for (int o = 1; o < 256; o <<= 1) {
    int u = (t >= o) ? stmp[t - o] : 0;
    __syncthreads();
    stmp[t] += u;
    __syncthreads();
  }
  boff[t] = stmp[t] - v;
  bcur[t] = stmp[t] - v;
  if (v > 0) gbase[t] = atomicAdd(&bin_cur[t], v);
  __syncthreads();
  for (int i = t; i < m; i += 256) {
    unsigned d = (unsigned)ei[E + e0 + i];
    int b = d >> BSH;
    int p = atomicAdd(&bcur[b], 1);
    unsigned short wh = __half_as_ushort(__float2half(ew[e0 + i]));
    spk[p] = (unsigned)ei[e0 + i] | ((unsigned)wh << 16);
    sdst[p] = (unsigned short)d;
  }
  __syncthreads();
  for (int i = t; i < m; i += 256) {
    unsigned short d = sdst[i];
    int b = d >> BSH;
    int g = gbase[b] + (i - boff[b]);
    pk_slab[g] = spk[i];
    dl_slab[g] = d;
  }
}

// one block per bin: local hist + scan -> beg/end[], scatter 4-byte
// records into the bin's own slab window of packed[] (L2-resident)
__global__ __launch_bounds__(256) void fine_csr_kernel(
    const unsigned* __restrict__ pk_slab,
    const unsigned short* __restrict__ dl_slab,
    const int* __restrict__ bin_cur, int* __restrict__ beg,
    int* __restrict__ endo, unsigned* __restrict__ packed, int N)
{
  __shared__ int cnt[256], loff[256], cur[256], stmp[256];
  int t = threadIdx.x;
  int b = blockIdx.x;
  int sbase = b * CAP;
  int m = bin_cur[b] - sbase;
  cnt[t] = 0;
  __syncthreads();
  for (int i = t; i < m; i += 256)
    atomicAdd(&cnt[dl_slab[sbase + i] & 255], 1);
  __syncthreads();
  int v = cnt[t];
  stmp[t] = v;
  __syncthreads();
  for (int o = 1; o < 256; o <<= 1) {
    int u = (t >= o) ? stmp[t - o] : 0;
    __syncthreads();
    stmp[t] += u;
    __syncthreads();
  }
  loff[t] = stmp[t] - v;
  cur[t] = loff[t];
  int node = b * BINW + t;
  if (node < N) {
    beg[node] = sbase + loff[t];
    endo[node] = sbase + loff[t] + v;
  }
  __syncthreads();
  for (int i = t; i < m; i += 256) {
    int dl = dl_slab[sbase + i] & 255;
    int p = atomicAdd(&cur[dl], 1);
    packed[sbase + p] = pk_slab[sbase + i];
  }
}

// ---------------- gather + z: TWO nodes per wave (2x MLP) ----------------
// 8 edge-subgroups x 8 lanes; lane holds 8 channels (16 B fp16 row).
// Two independent edge-list chains per lane hide L2-miss latency.
__global__ __launch_bounds__(256) void gather_kernel(
    const __half* __restrict__ hh, const unsigned* __restrict__ packed,
    const int* __restrict__ begA, const int* __restrict__ endA,
    const float* __restrict__ epsv, float* __restrict__ z, int layer, int N)
{
  int wave = threadIdx.x >> 6;
  int lane = threadIdx.x & 63;
  int sub = lane >> 3;          // 0..7
  int ch0 = (lane & 7) * 8;     // 8 channels per lane
  int na = blockIdx.x * 8 + wave * 2;
  int nb = na + 1;
  if (na >= N) return;
  bool hasB = nb < N;
  int bega = begA[na], enda = endA[na];
  int begb = hasB ? begA[nb] : 0, endb = hasB ? endA[nb] : 0;
  float accA[8] = {0, 0, 0, 0, 0, 0, 0, 0};
  float accB[8] = {0, 0, 0, 0, 0, 0, 0, 0};
  int ea = bega + sub, eb = begb + sub;
  while (ea < enda || eb < endb) {
    bool va = ea < enda;
    bool vb = eb < endb;
    unsigned pa = 0, pb = 0;
    if (va) pa = packed[ea];
    if (vb) pb = packed[eb];
    float4 ra, rb;
    if (va) ra = *(const float4*)(hh + (size_t)(pa & 0xffffu) * DD + ch0);
    if (vb) rb = *(const float4*)(hh + (size_t)(pb & 0xffffu) * DD + ch0);
    if (va) {
      float w = __half2float(__ushort_as_half((unsigned short)(pa >> 16)));
      const __half2* H = (const __half2*)&ra;
      #pragma unroll
      for (int j = 0; j < 4; ++j) {
        float2 f = __half22float2(H[j]);
        accA[2 * j]     = fmaf(w, f.x, accA[2 * j]);
        accA[2 * j + 1] = fmaf(w, f.y, accA[2 * j + 1]);
      }
    }
    if (vb) {
      float w = __half2float(__ushort_as_half((unsigned short)(pb >> 16)));
      const __half2* H = (const __half2*)&rb;
      #pragma unroll
      for (int j = 0; j < 4; ++j) {
        float2 f = __half22float2(H[j]);
        accB[2 * j]     = fmaf(w, f.x, accB[2 * j]);
        accB[2 * j + 1] = fmaf(w, f.y, accB[2 * j + 1]);
      }
    }
    ea += 8; eb += 8;
  }
  #pragma unroll
  for (int j = 0; j < 8; ++j) {
    accA[j] += __shfl_xor(accA[j], 8);
    accA[j] += __shfl_xor(accA[j], 16);
    accA[j] += __shfl_xor(accA[j], 32);
    accB[j] += __shfl_xor(accB[j], 8);
    accB[j] += __shfl_xor(accB[j], 16);
    accB[j] += __shfl_xor(accB[j], 32);
  }
  if (sub == 0) {
    float e1 = 1.0f + epsv[layer];
    {
      float4 sr = *(const float4*)(hh + (size_t)na * DD + ch0);
      const __half2* S = (const __half2*)&sr;
      float2 s0 = __half22float2(S[0]), s1 = __half22float2(S[1]);
      float2 s2 = __half22float2(S[2]), s3 = __half22float2(S[3]);
      float4 o0, o1;
      o0.x = fmaf(e1, s0.x, accA[0]); o0.y = fmaf(e1, s0.y, accA[1]);
      o0.z = fmaf(e1, s1.x, accA[2]); o0.w = fmaf(e1, s1.y, accA[3]);
      o1.x = fmaf(e1, s2.x, accA[4]); o1.y = fmaf(e1, s2.y, accA[5]);
      o1.z = fmaf(e1, s3.x, accA[6]); o1.w = fmaf(e1, s3.y, accA[7]);
      *(float4*)(z + (size_t)na * DD + ch0) = o0;
      *(float4*)(z + (size_t)na * DD + ch0 + 4) = o1;
    }
    if (hasB) {
      float4 sr = *(const float4*)(hh + (size_t)nb * DD + ch0);
      const __half2* S = (const __half2*)&sr;
      float2 s0 = __half22float2(S[0]), s1 = __half22float2(S[1]);
      float2 s2 = __half22float2(S[2]), s3 = __half22float2(S[3]);
      float4 o0, o1;
      o0.x = fmaf(e1, s0.x, accB[0]); o0.y = fmaf(e1, s0.y, accB[1]);
      o0.z = fmaf(e1, s1.x, accB[2]); o0.w = fmaf(e1, s1.y, accB[3]);
      o1.x = fmaf(e1, s2.x, accB[4]); o1.y = fmaf(e1, s2.y, accB[5]);
      o1.z = fmaf(e1, s3.x, accB[6]); o1.w = fmaf(e1, s3.y, accB[7]);
      *(float4*)(z + (size_t)nb * DD + ch0) = o0;
      *(float4*)(z + (size_t)nb * DD + ch0 + 4) = o1;
    }
  }
}

// ---------------- per-node GIN MLP + pooling ----------------
// Block = 256 (4 waves) = 64 nodes; waves split 64 output channels
// (16 each). c0 in SGPR via readfirstlane -> all W/BN loads scalar.
// Output h written fp16 only (next gather + final center both fp16-ok).
__global__ __launch_bounds__(256) void node_kernel(
    const float* __restrict__ z, __half* __restrict__ hhout,
    const float* __restrict__ W1, const float* __restrict__ b1,
    const float* __restrict__ gamma, const float* __restrict__ beta,
    const float* __restrict__ bnm, const float* __restrict__ bnv,
    const float* __restrict__ W2, const float* __restrict__ b2,
    const float* __restrict__ pmask, const int* __restrict__ batch,
    float* __restrict__ hcat, int layer, int N)
{
  __shared__ float tileZ[DD * DD];
  __shared__ float tileT[DD * DD];
  const int wave = threadIdx.x >> 6;
  const int lane = threadIdx.x & 63;
  const int n0 = blockIdx.x * 64;
  const int c0 = __builtin_amdgcn_readfirstlane(wave * 16);  // SGPR
  const float* W1l = W1 + layer * DD * DD;
  const float* W2l = W2 + layer * DD * DD;

  #pragma unroll
  for (int i = 0; i < 16; ++i) {
    int r = c0 + i;
    int n = n0 + r;
    float v = (n < N) ? z[(size_t)n * DD + lane] : 0.0f;
    tileZ[r * DD + ((lane + r) & 63)] = v;
  }
  __syncthreads();

  float t[16];
  #pragma unroll
  for (int cc = 0; cc < 16; ++cc) t[cc] = 0.0f;
  #pragma unroll 2
  for (int k = 0; k < DD; ++k) {
    float zk = tileZ[lane * DD + ((k + lane) & 63)];
    #pragma unroll
    for (int cc = 0; cc < 16; ++cc)
      t[cc] = fmaf(zk, W1l[k * DD + c0 + cc], t[cc]);   // scalar W
  }
  #pragma unroll
  for (int cc = 0; cc < 16; ++cc) {
    int c = c0 + cc;
    float A = gamma[layer * DD + c] * rsqrtf(bnv[layer * DD + c] + 1e-5f);
    float B = fmaf(b1[layer * DD + c] - bnm[layer * DD + c], A,
                   beta[layer * DD + c]);
    tileT[lane * DD + ((c + lane) & 63)] = fmaxf(fmaf(t[cc], A, B), 0.0f);
  }
  __syncthreads();

  #pragma unroll
  for (int cc = 0; cc < 16; ++cc) t[cc] = 0.0f;
  #pragma unroll 2
  for (int k = 0; k < DD; ++k) {
    float zk = tileT[lane * DD + ((k + lane) & 63)];
    #pragma unroll
    for (int cc = 0; cc < 16; ++cc)
      t[cc] = fmaf(zk, W2l[k * DD + c0 + cc], t[cc]);   // scalar W
  }
  #pragma unroll
  for (int cc = 0; cc < 16; ++cc) {
    int c = c0 + cc;
    tileZ[lane * DD + ((c + lane) & 63)] =
        fmaxf(t[cc] + b2[layer * DD + c], 0.0f);
  }
  __syncthreads();

  float accp = 0.0f;
  int gcur = -1;
  for (int i = 0; i < 16; ++i) {
    int r = c0 + i;
    int n = n0 + r;
    if (n >= N) break;
    float v = tileZ[r * DD + ((lane + r) & 63)];
    hhout[(size_t)n * DD + lane] = __float2half(v);
    int g = batch[n];                    // wave-uniform -> s_load
    if (g != gcur) {
      if (gcur >= 0) atomicAdd(&hcat[gcur * HC + layer * 128 + lane], accp);
      gcur = g; accp = 0.0f;
    }
    accp = fmaf(v, pmask[n], accp);
  }
  if (gcur >= 0) atomicAdd(&hcat[gcur * HC + layer * 128 + lane], accp);
}

// ---------------- final linear (+ fp16 center gather fused) ----------------
__global__ __launch_bounds__(256) void final_kernel(
    const float* __restrict__ hcat, const __half* __restrict__ h1,
    const __half* __restrict__ h2, const __half* __restrict__ h3,
    const int* __restrict__ mapping, const float* __restrict__ lw,
    const float* __restrict__ lb, float* __restrict__ out, int G)
{
  int gid = blockIdx.x * 256 + threadIdx.x;
  int g = gid >> 5, s = gid & 31;
  if (g >= G) return;
  float acc = lb[s];
  size_t mrow = (size_t)mapping[g] * DD;
  #pragma unroll
  for (int l = 0; l < 3; ++l) {
    const float* hc = hcat + g * HC + l * 128;
    const float* lwa = lw + (l * 128) * SS + s;
    #pragma unroll 4
    for (int c = 0; c < 64; ++c)
      acc = fmaf(hc[c], lwa[c * SS], acc);
    const __half* hr = ((l == 0) ? h1 : ((l == 1) ? h2 : h3)) + mrow;
    const float* lwc = lw + (l * 128 + 64) * SS + s;
    #pragma unroll 4
    for (int c = 0; c < 64; ++c)
      acc = fmaf(__half2float(hr[c]), lwc[c * SS], acc);
  }
  out[g * SS + s] = acc;
}

extern "C" void kernel_launch(void* const* d_in, const int* in_sizes, int n_in,
                              void* d_out, int out_size, void* d_ws, size_t ws_size,
                              hipStream_t stream)
{
  const float* x     = (const float*)d_in[0];
  const float* ew    = (const float*)d_in[1];
  const float* pmask = (const float*)d_in[2];
  const float* W1    = (const float*)d_in[3];
  const float* b1    = (const float*)d_in[4];
  const float* gma   = (const float*)d_in[5];
  const float* bta   = (const float*)d_in[6];
  const float* bnm   = (const float*)d_in[7];
  const float* bnv   = (const float*)d_in[8];
  const float* W2    = (const float*)d_in[9];
  const float* b2    = (const float*)d_in[10];
  const float* epsv  = (const float*)d_in[11];
  const float* lw    = (const float*)d_in[12];
  const float* lb    = (const float*)d_in[13];
  const int*   ei    = (const int*)d_in[14];
  const int*   batch = (const int*)d_in[15];
  const int*   mapping = (const int*)d_in[16];

  const int N = in_sizes[2];     // 50000 (< 65536 required for packing)
  const int E = in_sizes[1];
  const int G = in_sizes[16];
  const int nbins = (N + BINW - 1) / BINW;   // 196 <= 256
  const int nchunks = (E + CHUNK - 1) / CHUNK;

  __half*   hh0  = (__half*)d_ws;                     // N*DD fp16
  __half*   hh1  = hh0 + (size_t)N * DD;              // N*DD
  __half*   hh2  = hh1 + (size_t)N * DD;              // N*DD
  __half*   hh3  = hh2 + (size_t)N * DD;              // N*DD
  float*    zscr = (float*)(hh3 + (size_t)N * DD);    // N*DD fp32
  float*    hcat = zscr + (size_t)N * DD;             // G*HC
  int*      beg  = (int*)(hcat + (size_t)G * HC);     // N
  int*      endo = beg + N;                           // N
  int*      bin_cur = endo + N;                       // nbins (+pad)
  unsigned* packed  = (unsigned*)(bin_cur + 256);     // nbins*CAP
  unsigned* pk_slab = packed + (size_t)nbins * CAP;   // nbins*CAP
  unsigned short* dl_slab =
      (unsigned short*)(pk_slab + (size_t)nbins * CAP); // nbins*CAP
  float* fout = (float*)d_out;

  // ---- prep (bin_cur init + hcat zero + x->fp16), 1 dispatch ----
  prep_kernel<<<(N * DD / 8 + 255) / 256, 256, 0, stream>>>(
      x, hh0, bin_cur, hcat, nbins, G * HC / 4, N * DD);

  // ---- slab-binned CSR build (2 dispatches) ----
  bin_part_kernel<<<nchunks, 256, 0, stream>>>(ei, ew, bin_cur,
                                               pk_slab, dl_slab, E);
  fine_csr_kernel<<<nbins, 256, 0, stream>>>(pk_slab, dl_slab, bin_cur,
                                             beg, endo, packed, N);

  // ---- 3 GIN layers ----
  __half* hhs[4] = {hh0, hh1, hh2, hh3};
  for (int layer = 0; layer < 3; ++layer) {
    gather_kernel<<<(N + 7) / 8, 256, 0, stream>>>(
        hhs[layer], packed, beg, endo, epsv, zscr, layer, N);
    node_kernel<<<(N + 63) / 64, 256, 0, stream>>>(
        zscr, hhs[layer + 1], W1, b1, gma, bta, bnm, bnv, W2, b2,
        pmask, batch, hcat, layer, N);
  }
  final_kernel<<<(G * SS + 255) / 256, 256, 0, stream>>>(
      hcat, hh1, hh2, hh3, mapping, lw, lb, fout, G);
}